// Round 13
// baseline (169.410 us; speedup 1.0000x reference)
//
#include <hip/hip_runtime.h>

// MHA fused forward for B=4,T=2048,E=1024,H=16,D=64 on gfx950.
// prep (merged) -> GEMM1 (QKV, 128x128 block, 2 waves x 128x64 wave-tile, BK=32 dbuf,
// 4 blocks/CU) -> flash attn (32x32 MFMA, tri-buffer K/V, counted vmcnt) -> GEMM2 (same GEMM).

typedef __attribute__((ext_vector_type(8))) __bf16 bf16x8;
typedef __attribute__((ext_vector_type(4))) float f32x4;
typedef __attribute__((ext_vector_type(16))) float f32x16;
typedef __attribute__((ext_vector_type(4))) unsigned int u32x4;
typedef __attribute__((ext_vector_type(2))) unsigned int u32x2;
typedef unsigned short u16;
typedef unsigned int u32;

#define DEV __device__ __forceinline__

#define QK_SCALE 0.18033688011112042f   // 0.125 * log2(e) : folded into Wq/bq

DEV u16 f2bf(float f) {          // round-to-nearest-even f32 -> bf16 (inputs never NaN)
  u32 u = __builtin_bit_cast(u32, f);
  u += 0x7fffu + ((u >> 16) & 1u);
  return (u16)(u >> 16);
}
DEV u32 pack2(float a, float b) { return (u32)f2bf(a) | ((u32)f2bf(b) << 16); }

DEV float exp2_hw(float x) { float r; asm("v_exp_f32 %0, %1" : "=v"(r) : "v"(x)); return r; }
DEV u32 cvtpk_bf16(float lo, float hi) {
  u32 r; asm("v_cvt_pk_bf16_f32 %0, %1, %2" : "=v"(r) : "v"(lo), "v"(hi)); return r;
}
DEV void pl32swap(u32& a, u32& b) { asm("v_permlane32_swap_b32 %0, %1" : "+v"(a), "+v"(b)); }
DEV float max3f(float a, float b, float c) {
  float r; asm("v_max3_f32 %0, %1, %2, %3" : "=v"(r) : "v"(a), "v"(b), "v"(c)); return r;
}

DEV f32x16 zero16() { f32x16 z;
#pragma unroll
  for (int i = 0; i < 16; i++) z[i] = 0.f;
  return z; }

DEV void gll16(const u16* g, u16* l) {
  __builtin_amdgcn_global_load_lds((const __attribute__((address_space(1))) void*)g,
                                   (__attribute__((address_space(3))) void*)l, 16, 0, 0);
}

#define SCHEDB() __builtin_amdgcn_sched_barrier(0)
#define FENCE4()  do { asm volatile("s_waitcnt vmcnt(4) lgkmcnt(0)" ::: "memory"); SCHEDB(); \
                       __builtin_amdgcn_s_barrier(); SCHEDB(); } while (0)
#define FENCE0()  do { asm volatile("s_waitcnt vmcnt(0) lgkmcnt(0)" ::: "memory"); SCHEDB(); \
                       __builtin_amdgcn_s_barrier(); SCHEDB(); } while (0)

// ---------------------------------------------------------------- prep (merged): x->bf16 + biases,
// then weight transposes. Blocks 0..4095: x; 4096..5119: weights.
__global__ __launch_bounds__(256) void prep_all_kernel(
    const float* __restrict__ x, const float* __restrict__ bq, const float* __restrict__ bk,
    const float* __restrict__ bv, const float* __restrict__ Wq, const float* __restrict__ Wk,
    const float* __restrict__ Wv, const float* __restrict__ Wp,
    u16* __restrict__ xbf, float* __restrict__ bqkv, u16* __restrict__ wqkvT, u16* __restrict__ wpT) {
  __shared__ float t[64][65];
  int bidAll = blockIdx.x, tid = threadIdx.x;
  if (bidAll < 4096) {
    int gid = bidAll * 256 + tid;
    if (gid < 3072) {
      float v = (gid < 1024) ? bq[gid] * QK_SCALE : (gid < 2048 ? bk[gid - 1024] : bv[gid - 2048]);
      bqkv[gid] = v;
    }
    const float4* xv = (const float4*)x;
    float4 f0 = xv[(size_t)gid * 2];
    float4 f1 = xv[(size_t)gid * 2 + 1];
    u32x4 st;
    st.x = pack2(f0.x, f0.y); st.y = pack2(f0.z, f0.w);
    st.z = pack2(f1.x, f1.y); st.w = pack2(f1.z, f1.w);
    *(u32x4*)&xbf[(size_t)gid * 8] = st;
    return;
  }
  int bid = bidAll - 4096;
  int r0 = tid >> 6, c = tid & 63;
  if (bid < 768) {
    int p = bid >> 8, rem = bid & 255, h = rem >> 4, et = rem & 15;
    float sc = (p == 0) ? QK_SCALE : 1.0f;
    const float* src = (p == 0 ? Wq : (p == 1 ? Wk : Wv)) + ((size_t)h * 1024 + et * 64) * 64;
#pragma unroll
    for (int i = 0; i < 16; i++) { int e = r0 + i * 4; t[e][c] = src[(size_t)e * 64 + c]; }
    __syncthreads();
    u16* dst = wqkvT + ((size_t)p * 1024 + h * 64) * 1024 + et * 64;
#pragma unroll
    for (int i = 0; i < 16; i++) { int d = r0 + i * 4; dst[(size_t)d * 1024 + c] = f2bf(t[c][d] * sc); }
  } else {
    int b2 = bid - 768, rt = b2 >> 4, ct = b2 & 15;
#pragma unroll
    for (int i = 0; i < 16; i++) { int e = r0 + i * 4; t[e][c] = Wp[(size_t)(rt * 64 + e) * 1024 + ct * 64 + c]; }
    __syncthreads();
#pragma unroll
    for (int i = 0; i < 16; i++) { int f = r0 + i * 4; wpT[(size_t)(ct * 64 + f) * 1024 + rt * 64 + c] = f2bf(t[c][f]); }
  }
}

// ---------------------------------------------------------------- GEMM 128x128 block, 2 waves,
// wave tile 128x64 (wave wn owns cols [wn*64, +64); reads ALL 8 A-frags + its 4 B-frags).
// LDS reads/FLOP = 0.0229 B (1.33x less than the 64x64-wave-tile family), staging writes
// halve. BK=32, dbuf 32KB -> 4 blocks/CU (2 waves/SIMD). R8's proven loop skeleton:
// issue stage(t+1) first (flies under MFMA), ds_read frags, 32 MFMA, __syncthreads.
// Pair-interleaved swizzle (verified R11/R12): line L holds rows {2L,2L+1}, slot ^= (L&3).
DEV void stage_tile32(const u16* __restrict__ X, int row0, int k0, u16* lds, int tid) {
#pragma unroll
  for (int j = 0; j < 4; j++) {
    int ci = j * 128 + tid;            // 512 chunks of 16B = 64 lines x {half,slot}
    int L = ci >> 3, half = (ci >> 2) & 1, s = ci & 3;
    int row = L * 2 + half;
    int srcslot = s ^ (L & 3);
    gll16(X + (size_t)(row0 + row) * 1024 + k0 + srcslot * 8, lds + ci * 8);
  }
}

DEV int frag_off32(int row, int lg) {   // u16 index of (row, logical slot lg) in tile
  return (row >> 1) * 64 + (row & 1) * 32 + ((lg ^ ((row >> 1) & 3)) * 8);
}

__global__ __launch_bounds__(128, 2) void gemm128_kernel(
    const u16* __restrict__ A, const u16* __restrict__ Bt, const float* __restrict__ bias,
    int tilesN, int mode, u16* __restrict__ Qb, u16* __restrict__ Kb, u16* __restrict__ VTb,
    float* __restrict__ outF) {
  __shared__ u16 As[2][128 * 32];
  __shared__ u16 Bs[2][128 * 32];
  int nwg = gridDim.x;
  int bid = blockIdx.x;
  int swz = (bid % 8) * (nwg / 8) + bid / 8;
  int bm = swz / tilesN, bn = swz % tilesN;
  int tid = threadIdx.x;
  int lane = tid & 63;
  int wn = tid >> 6;                    // 2 waves: N-split
  int lr = lane & 15, lg = lane >> 4;

  f32x4 acc[8][4];
#pragma unroll
  for (int i = 0; i < 8; i++)
#pragma unroll
    for (int j = 0; j < 4; j++) acc[i][j] = f32x4{0.f, 0.f, 0.f, 0.f};

  int aoff[8], boff[4];
#pragma unroll
  for (int i = 0; i < 8; i++) aoff[i] = frag_off32(i * 16 + lr, lg);
#pragma unroll
  for (int j = 0; j < 4; j++) boff[j] = frag_off32(wn * 64 + j * 16 + lr, lg);

  stage_tile32(A, bm * 128, 0, As[0], tid);
  stage_tile32(Bt, bn * 128, 0, Bs[0], tid);
  __syncthreads();
  int cur = 0;

  for (int t = 0; t < 32; ++t) {
    if (t + 1 < 32) {                   // issue next-tile loads first: fly under MFMA
      stage_tile32(A, bm * 128, (t + 1) * 32, As[cur ^ 1], tid);
      stage_tile32(Bt, bn * 128, (t + 1) * 32, Bs[cur ^ 1], tid);
    }
    bf16x8 af[8], bfr[4];
#pragma unroll
    for (int i = 0; i < 8; i++) af[i] = *(const bf16x8*)&As[cur][aoff[i]];
#pragma unroll
    for (int j = 0; j < 4; j++) bfr[j] = *(const bf16x8*)&Bs[cur][boff[j]];
    __builtin_amdgcn_s_setprio(1);
#pragma unroll
    for (int i = 0; i < 8; i++)
#pragma unroll
      for (int j = 0; j < 4; j++)
        acc[i][j] = __builtin_amdgcn_mfma_f32_16x16x32_bf16(af[i], bfr[j], acc[i][j], 0, 0, 0);
    __builtin_amdgcn_s_setprio(0);
    __syncthreads();
    cur ^= 1;
  }

  int ccolb = bn * 128 + wn * 64;
  if (mode == 0) {   // QKV epilogue: +bias, ->bf16, scatter Q/K [bh][t][d], V -> VT [bh][d][t]
#pragma unroll
    for (int j = 0; j < 4; j++) {
      int col = ccolb + j * 16 + lr;
      float bb = bias[col];
      int p = col >> 10, h = (col >> 6) & 15, d = col & 63;
#pragma unroll
      for (int i = 0; i < 8; i++) {
        int row0 = bm * 128 + i * 16 + lg * 4;
        int b_ = row0 >> 11, t0 = row0 & 2047;
        if (p == 2) {
          u32x2 pv;
          pv.x = pack2(acc[i][j][0] + bb, acc[i][j][1] + bb);
          pv.y = pack2(acc[i][j][2] + bb, acc[i][j][3] + bb);
          *(u32x2*)&VTb[((size_t)(b_ * 16 + h) * 64 + d) * 2048 + t0] = pv;
        } else {
          u16* dst = (p == 0 ? Qb : Kb);
#pragma unroll
          for (int r = 0; r < 4; r++)
            dst[((size_t)(b_ * 16 + h) * 2048 + (t0 + r)) * 64 + d] = f2bf(acc[i][j][r] + bb);
        }
      }
    }
  } else {           // final projection epilogue: +bias, fp32 out
#pragma unroll
    for (int j = 0; j < 4; j++) {
      int col = ccolb + j * 16 + lr;
      float bb = bias[col];
#pragma unroll
      for (int i = 0; i < 8; i++) {
        int row0 = bm * 128 + i * 16 + lg * 4;
#pragma unroll
        for (int r = 0; r < 4; r++)
          outF[(size_t)(row0 + r) * 1024 + col] = acc[i][j][r] + bb;
      }
    }
  }
}

// ---------------------------------------------------------------- flash attention (causal, 32x32)
// 1024 blocks of 4 waves; block = one 128-row q-tile t of one (b,h); iters = 2t+2 (>= 2).
// TRI-buffered K/V (48KB, 3 blocks/CU), prefetch distance 2, counted vmcnt(4) fences.
// Fully-masked tiles skip compute wave-uniformly; diagonal mask on last two iters only.
DEV void stage_kv256(const u16* __restrict__ Kh, const u16* __restrict__ Vh, int kv0,
                     u16* Ksb, u16* Vsb, int tid) {
#pragma unroll
  for (int j = 0; j < 2; j++) {
    int ci = j * 256 + tid;                 // 512 chunks of 16B = 64 rows x 8 slots
    int row = ci >> 3, slot = ci & 7;
    int ss = slot ^ (row & 7);
    gll16(Kh + (size_t)(kv0 + row) * 64 + ss * 8, Ksb + ci * 8);
    gll16(Vh + (size_t)row * 2048 + kv0 + ss * 8, Vsb + ci * 8);
  }
}

__global__ __launch_bounds__(256, 2) void attn_kernel(
    const u16* __restrict__ Qb, const u16* __restrict__ Kb, const u16* __restrict__ VTb,
    u16* __restrict__ cat) {
  __shared__ u16 Ks[3][64 * 64];
  __shared__ u16 Vs[3][64 * 64];
  int bid = blockIdx.x;                 // 1024 = 16 t x 64 bh, longest-first
  int t = 15 - (bid >> 6);              // q-tile index: rows [128t, 128t+128)
  int bh = bid & 63;
  int b = bh >> 4, h = bh & 15;
  int tid = threadIdx.x, wave = tid >> 6, lane = tid & 63;
  int l31 = lane & 31, hi = lane >> 5;
  int q0w = t * 128 + wave * 32;        // wave's 32-row q-slice
  int qrow = q0w + l31;

  const u16* Qh = Qb + (size_t)bh * 2048 * 64;
  const u16* Kh = Kb + (size_t)bh * 2048 * 64;
  const u16* Vh = VTb + (size_t)bh * 64 * 2048;

  bf16x8 qf[4];                         // B-operand: col=q (lane&31), k = ks*16 + hi*8 + i
#pragma unroll
  for (int ks = 0; ks < 4; ks++)
    qf[ks] = *(const bf16x8*)&Qh[(size_t)qrow * 64 + ks * 16 + hi * 8];

  u32 loff[4];                          // swizzled LDS byte offsets (row l31; +4096B for +32)
#pragma unroll
  for (int ks = 0; ks < 4; ks++)
    loff[ks] = (u32)(l31 * 128 + (((ks * 2 + hi) ^ (l31 & 7)) * 16));

  f32x16 o0 = zero16(), o1 = zero16();
  float m_run = -1e30f, l_run = 0.f;
  int iters = 2 * t + 2;                // always >= 2

  stage_kv256(Kh, Vh, 0, Ks[0], Vs[0], tid);
  stage_kv256(Kh, Vh, 64, Ks[1], Vs[1], tid);
  asm volatile("s_waitcnt vmcnt(4)" ::: "memory");   // tile 0 landed; tile 1 in flight
  SCHEDB();
  __builtin_amdgcn_s_barrier();
  SCHEDB();

  int rs = 0;
  for (int kvt = 0; kvt < iters; ++kvt) {
    int kv0 = kvt * 64;
    int ws = rs + 2; if (ws >= 3) ws -= 3;
    bool st = (kvt + 2) < iters;
    if (st) stage_kv256(Kh, Vh, kv0 + 128, Ks[ws], Vs[ws], tid);

    if (kv0 <= q0w + 31) {              // wave-uniform: skip fully-masked tiles
      f32x16 s0 = zero16(), s1 = zero16();
      const char* kb = (const char*)&Ks[rs][0];
      __builtin_amdgcn_s_setprio(1);
#pragma unroll
      for (int ks = 0; ks < 4; ks++) {
        bf16x8 k0 = *(const bf16x8*)(kb + loff[ks]);
        bf16x8 k1 = *(const bf16x8*)(kb + loff[ks] + 4096);
        s0 = __builtin_amdgcn_mfma_f32_32x32x16_bf16(k0, qf[ks], s0, 0, 0, 0);
        s1 = __builtin_amdgcn_mfma_f32_32x32x16_bf16(k1, qf[ks], s1, 0, 0, 0);
      }
      __builtin_amdgcn_s_setprio(0);

      if (kv0 + 63 > q0w) {             // diagonal tile(s) only
        int relh = qrow - kv0 - 4 * hi;
#pragma unroll
        for (int r = 0; r < 16; r++) {
          int off = (r & 3) + 8 * (r >> 2);
          s0[r] = (off > relh) ? -1e30f : s0[r];
          s1[r] = (off + 32 > relh) ? -1e30f : s1[r];
        }
      }

      float ta = max3f(s0[0], s0[1], s0[2]);
      float tb = max3f(s0[4], s0[5], s0[6]);
      float tc = max3f(s0[8], s0[9], s0[10]);
      float td = max3f(s0[12], s0[13], s0[14]);
      ta = max3f(ta, s0[3], s1[0]);
      tb = max3f(tb, s0[7], s1[4]);
      tc = max3f(tc, s0[11], s1[8]);
      td = max3f(td, s0[15], s1[12]);
      ta = max3f(ta, s1[1], s1[2]);
      tb = max3f(tb, s1[5], s1[6]);
      tc = max3f(tc, s1[9], s1[10]);
      td = max3f(td, s1[13], s1[14]);
      ta = max3f(ta, s1[3], tb);
      tc = max3f(tc, s1[7], td);
      float tmax = max3f(ta, tc, s1[11]);
      tmax = fmaxf(tmax, s1[15]);
      tmax = fmaxf(tmax, __shfl_xor(tmax, 32));
      float corr = 1.f;
      if (!__all(tmax <= m_run + 8.f)) {
        float m_new = fmaxf(m_run, tmax);
        corr = exp2_hw(m_run - m_new);
        o0 = o0 * corr;
        o1 = o1 * corr;
        m_run = m_new;
      }
      float t0 = 0.f, t1 = 0.f, t2 = 0.f, t3 = 0.f;
#pragma unroll
      for (int j = 0; j < 4; j++) {
        float p00 = exp2_hw(s0[j * 4 + 0] - m_run); s0[j * 4 + 0] = p00; t0 += p00;
        float p01 = exp2_hw(s0[j * 4 + 1] - m_run); s0[j * 4 + 1] = p01; t1 += p01;
        float p02 = exp2_hw(s0[j * 4 + 2] - m_run); s0[j * 4 + 2] = p02; t2 += p02;
        float p03 = exp2_hw(s0[j * 4 + 3] - m_run); s0[j * 4 + 3] = p03; t3 += p03;
        float p10 = exp2_hw(s1[j * 4 + 0] - m_run); s1[j * 4 + 0] = p10; t0 += p10;
        float p11 = exp2_hw(s1[j * 4 + 1] - m_run); s1[j * 4 + 1] = p11; t1 += p11;
        float p12 = exp2_hw(s1[j * 4 + 2] - m_run); s1[j * 4 + 2] = p12; t2 += p12;
        float p13 = exp2_hw(s1[j * 4 + 3] - m_run); s1[j * 4 + 3] = p13; t3 += p13;
      }
      float ts = (t0 + t1) + (t2 + t3);
      ts += __shfl_xor(ts, 32);
      l_run = l_run * corr + ts;

      const char* vb = (const char*)&Vs[rs][0];
      __builtin_amdgcn_s_setprio(1);
#pragma unroll
      for (int ks = 0; ks < 4; ks++) {
        const f32x16& sb = (ks < 2) ? s0 : s1;
        int g2 = (ks & 1) * 8;
        u32 a  = cvtpk_bf16(sb[g2 + 0], sb[g2 + 1]);
        u32 c  = cvtpk_bf16(sb[g2 + 2], sb[g2 + 3]);
        u32 bb = cvtpk_bf16(sb[g2 + 4], sb[g2 + 5]);
        u32 d  = cvtpk_bf16(sb[g2 + 6], sb[g2 + 7]);
        pl32swap(a, bb);
        pl32swap(c, d);
        u32x4 wv; wv.x = a; wv.y = c; wv.z = bb; wv.w = d;
        bf16x8 pf = __builtin_bit_cast(bf16x8, wv);
        bf16x8 v0 = *(const bf16x8*)(vb + loff[ks]);
        bf16x8 v1 = *(const bf16x8*)(vb + loff[ks] + 4096);
        o0 = __builtin_amdgcn_mfma_f32_32x32x16_bf16(v0, pf, o0, 0, 0, 0);
        o1 = __builtin_amdgcn_mfma_f32_32x32x16_bf16(v1, pf, o1, 0, 0, 0);
      }
      __builtin_amdgcn_s_setprio(0);
    }

    if (st) FENCE4(); else FENCE0();
    rs = rs + 1; if (rs >= 3) rs -= 3;
  }

  float li = 1.0f / l_run;
#pragma unroll
  for (int m = 0; m < 8; m++) {
    int dbase = 2 * (m & 1) + 8 * (m >> 1) + 4 * hi;
    u32 w0 = cvtpk_bf16(o0[2 * m] * li, o0[2 * m + 1] * li);
    u32 w1 = cvtpk_bf16(o1[2 * m] * li, o1[2 * m + 1] * li);
    *(u32*)&cat[(size_t)(b * 2048 + qrow) * 1024 + h * 64 + dbase] = w0;
    *(u32*)&cat[(size_t)(b * 2048 + qrow) * 1024 + h * 64 + 32 + dbase] = w1;
  }
}

// ---------------------------------------------------------------- launch
extern "C" void kernel_launch(void* const* d_in, const int* in_sizes, int n_in,
                              void* d_out, int out_size, void* d_ws, size_t ws_size,
                              hipStream_t stream) {
  const float* x  = (const float*)d_in[0];
  const float* Wq = (const float*)d_in[1];
  const float* bq = (const float*)d_in[2];
  const float* Wk = (const float*)d_in[3];
  const float* bk = (const float*)d_in[4];
  const float* Wv = (const float*)d_in[5];
  const float* bv = (const float*)d_in[6];
  const float* Wp = (const float*)d_in[7];
  const float* bp = (const float*)d_in[8];

  char* w = (char*)d_ws;
  u16* xbf    = (u16*)w;                 w += (size_t)8192 * 1024 * 2;
  u16* wqkvT  = (u16*)w;                 w += (size_t)3072 * 1024 * 2;
  u16* wpT    = (u16*)w;                 w += (size_t)1024 * 1024 * 2;
  float* bqkv = (float*)w;               w += (size_t)3072 * 4;
  u16* Qb     = (u16*)w;                 w += (size_t)64 * 2048 * 64 * 2;
  u16* Kb     = (u16*)w;                 w += (size_t)64 * 2048 * 64 * 2;
  u16* VTb    = (u16*)w;                 w += (size_t)64 * 64 * 2048 * 2;
  u16* cat    = (u16*)w;                 w += (size_t)8192 * 1024 * 2;

  prep_all_kernel<<<5120, 256, 0, stream>>>(x, bq, bk, bv, Wq, Wk, Wv, Wp, xbf, bqkv, wqkvT, wpT);
  gemm128_kernel<<<1536, 128, 0, stream>>>(xbf, wqkvT, bqkv, 24, 0, Qb, Kb, VTb, nullptr);
  attn_kernel<<<1024, 256, 0, stream>>>(Qb, Kb, VTb, cat);
  gemm128_kernel<<<512, 128, 0, stream>>>(cat, wpT, bp, 8, 1, nullptr, nullptr, nullptr, (float*)d_out);
}

// Round 14
// 165.966 us; speedup vs baseline: 1.0207x; 1.0207x over previous
//
#include <hip/hip_runtime.h>

// MHA fused forward for B=4,T=2048,E=1024,H=16,D=64 on gfx950.
// prep (merged) -> GEMM1 (QKV, 128x128 BK=64 dbuf, 4 waves, 32x32x16 MFMA, 2 blocks/CU) ->
// flash attn (32x32 MFMA, 4-wave 128-row q-tiles, dbuf K/V) -> GEMM2 (same GEMM).

typedef __attribute__((ext_vector_type(8))) __bf16 bf16x8;
typedef __attribute__((ext_vector_type(4))) float f32x4;
typedef __attribute__((ext_vector_type(16))) float f32x16;
typedef __attribute__((ext_vector_type(4))) unsigned int u32x4;
typedef __attribute__((ext_vector_type(2))) unsigned int u32x2;
typedef unsigned short u16;
typedef unsigned int u32;

#define DEV __device__ __forceinline__

#define QK_SCALE 0.18033688011112042f   // 0.125 * log2(e) : folded into Wq/bq

DEV u16 f2bf(float f) {          // round-to-nearest-even f32 -> bf16 (inputs never NaN)
  u32 u = __builtin_bit_cast(u32, f);
  u += 0x7fffu + ((u >> 16) & 1u);
  return (u16)(u >> 16);
}
DEV u32 pack2(float a, float b) { return (u32)f2bf(a) | ((u32)f2bf(b) << 16); }

DEV float exp2_hw(float x) { float r; asm("v_exp_f32 %0, %1" : "=v"(r) : "v"(x)); return r; }
DEV u32 cvtpk_bf16(float lo, float hi) {
  u32 r; asm("v_cvt_pk_bf16_f32 %0, %1, %2" : "=v"(r) : "v"(lo), "v"(hi)); return r;
}
DEV void pl32swap(u32& a, u32& b) { asm("v_permlane32_swap_b32 %0, %1" : "+v"(a), "+v"(b)); }
DEV float max3f(float a, float b, float c) {
  float r; asm("v_max3_f32 %0, %1, %2, %3" : "=v"(r) : "v"(a), "v"(b), "v"(c)); return r;
}

DEV f32x16 zero16() { f32x16 z;
#pragma unroll
  for (int i = 0; i < 16; i++) z[i] = 0.f;
  return z; }

DEV void gll16(const u16* g, u16* l) {
  __builtin_amdgcn_global_load_lds((const __attribute__((address_space(1))) void*)g,
                                   (__attribute__((address_space(3))) void*)l, 16, 0, 0);
}

// ---------------------------------------------------------------- prep (merged): x->bf16 + biases,
// then weight transposes. Blocks 0..4095: x; 4096..5119: weights.
__global__ __launch_bounds__(256) void prep_all_kernel(
    const float* __restrict__ x, const float* __restrict__ bq, const float* __restrict__ bk,
    const float* __restrict__ bv, const float* __restrict__ Wq, const float* __restrict__ Wk,
    const float* __restrict__ Wv, const float* __restrict__ Wp,
    u16* __restrict__ xbf, float* __restrict__ bqkv, u16* __restrict__ wqkvT, u16* __restrict__ wpT) {
  __shared__ float t[64][65];
  int bidAll = blockIdx.x, tid = threadIdx.x;
  if (bidAll < 4096) {
    int gid = bidAll * 256 + tid;
    if (gid < 3072) {
      float v = (gid < 1024) ? bq[gid] * QK_SCALE : (gid < 2048 ? bk[gid - 1024] : bv[gid - 2048]);
      bqkv[gid] = v;
    }
    const float4* xv = (const float4*)x;
    float4 f0 = xv[(size_t)gid * 2];
    float4 f1 = xv[(size_t)gid * 2 + 1];
    u32x4 st;
    st.x = pack2(f0.x, f0.y); st.y = pack2(f0.z, f0.w);
    st.z = pack2(f1.x, f1.y); st.w = pack2(f1.z, f1.w);
    *(u32x4*)&xbf[(size_t)gid * 8] = st;
    return;
  }
  int bid = bidAll - 4096;
  int r0 = tid >> 6, c = tid & 63;
  if (bid < 768) {
    int p = bid >> 8, rem = bid & 255, h = rem >> 4, et = rem & 15;
    float sc = (p == 0) ? QK_SCALE : 1.0f;
    const float* src = (p == 0 ? Wq : (p == 1 ? Wk : Wv)) + ((size_t)h * 1024 + et * 64) * 64;
#pragma unroll
    for (int i = 0; i < 16; i++) { int e = r0 + i * 4; t[e][c] = src[(size_t)e * 64 + c]; }
    __syncthreads();
    u16* dst = wqkvT + ((size_t)p * 1024 + h * 64) * 1024 + et * 64;
#pragma unroll
    for (int i = 0; i < 16; i++) { int d = r0 + i * 4; dst[(size_t)d * 1024 + c] = f2bf(t[c][d] * sc); }
  } else {
    int b2 = bid - 768, rt = b2 >> 4, ct = b2 & 15;
#pragma unroll
    for (int i = 0; i < 16; i++) { int e = r0 + i * 4; t[e][c] = Wp[(size_t)(rt * 64 + e) * 1024 + ct * 64 + c]; }
    __syncthreads();
#pragma unroll
    for (int i = 0; i < 16; i++) { int f = r0 + i * 4; wpT[(size_t)(ct * 64 + f) * 1024 + rt * 64 + c] = f2bf(t[c][f]); }
  }
}

// ---------------------------------------------------------------- GEMM 128x128, BK=64, dbuf,
// 4 waves of 64x64, 32x32x16 MFMA (2382 TF ceiling, half the issue slots of 16x16x32 at the
// same 16 b128-reads per wave per K64). R9's proven loop: issue stage(t+1) first, ds_read,
// MFMA, __syncthreads. XOR swizzle slot^=(row&7) both sides (rule #21; 0 conflicts measured).
// Layouts HW-verified in the attn kernel: A row=lane&31 k=(lane>>5)*8+i; B col analog;
// C/D col=lane&31, row=(reg&3)+8*(reg>>2)+4*(lane>>5).
DEV void stage_tile(const u16* __restrict__ X, int row0, int k0, u16* lds, int tid) {
#pragma unroll
  for (int j = 0; j < 4; j++) {
    int ci = j * 256 + tid;
    int row = ci >> 3, slot = ci & 7;
    int srcslot = slot ^ (row & 7);
    gll16(X + (size_t)(row0 + row) * 1024 + k0 + srcslot * 8, lds + ci * 8);
  }
}

__global__ __launch_bounds__(256, 2) void gemm128_kernel(
    const u16* __restrict__ A, const u16* __restrict__ Bt, const float* __restrict__ bias,
    int tilesN, int mode, u16* __restrict__ Qb, u16* __restrict__ Kb, u16* __restrict__ VTb,
    float* __restrict__ outF) {
  __shared__ u16 As[2][128 * 64];
  __shared__ u16 Bs[2][128 * 64];
  int nwg = gridDim.x;
  int bid = blockIdx.x;
  int swz = (bid % 8) * (nwg / 8) + bid / 8;
  int bm = swz / tilesN, bn = swz % tilesN;
  int tid = threadIdx.x;
  int lane = tid & 63, wave = tid >> 6;
  int wm = wave >> 1, wn = wave & 1;
  int l31 = lane & 31, hi = lane >> 5;

  f32x16 acc[2][2];
#pragma unroll
  for (int i = 0; i < 2; i++)
#pragma unroll
    for (int j = 0; j < 2; j++) acc[i][j] = zero16();

  // LDS u16-offsets for (row = base + i*32 + l31, k-slot = ks*2 + hi), swizzled
  int aoff[2][4], boff[2][4];
#pragma unroll
  for (int i = 0; i < 2; i++)
#pragma unroll
    for (int ks = 0; ks < 4; ks++) {
      int ra = wm * 64 + i * 32 + l31;
      aoff[i][ks] = ra * 64 + (((ks * 2 + hi) ^ (ra & 7)) * 8);
      int rb = wn * 64 + i * 32 + l31;
      boff[i][ks] = rb * 64 + (((ks * 2 + hi) ^ (rb & 7)) * 8);
    }

  stage_tile(A, bm * 128, 0, As[0], tid);
  stage_tile(Bt, bn * 128, 0, Bs[0], tid);
  __syncthreads();
  int cur = 0;

  for (int t = 0; t < 16; ++t) {
    if (t + 1 < 16) {                   // issue next-tile loads first: fly under MFMA
      stage_tile(A, bm * 128, (t + 1) * 64, As[cur ^ 1], tid);
      stage_tile(Bt, bn * 128, (t + 1) * 64, Bs[cur ^ 1], tid);
    }
    bf16x8 af[2][4], bfr[2][4];
#pragma unroll
    for (int i = 0; i < 2; i++)
#pragma unroll
      for (int ks = 0; ks < 4; ks++) {
        af[i][ks] = *(const bf16x8*)&As[cur][aoff[i][ks]];
        bfr[i][ks] = *(const bf16x8*)&Bs[cur][boff[i][ks]];
      }
    __builtin_amdgcn_s_setprio(1);
#pragma unroll
    for (int ks = 0; ks < 4; ks++)
#pragma unroll
      for (int i = 0; i < 2; i++)
#pragma unroll
        for (int j = 0; j < 2; j++)
          acc[i][j] = __builtin_amdgcn_mfma_f32_32x32x16_bf16(af[i][ks], bfr[j][ks], acc[i][j], 0, 0, 0);
    __builtin_amdgcn_s_setprio(0);
    __syncthreads();
    cur ^= 1;
  }

  // C/D: col = ccol + l31, row = rowb + (r&3) + 8*(r>>2) + 4*hi
  if (mode == 0) {   // QKV epilogue: +bias, ->bf16, scatter Q/K [bh][t][d], V -> VT [bh][d][t]
#pragma unroll
    for (int j = 0; j < 2; j++) {
      int col = bn * 128 + wn * 64 + j * 32 + l31;
      float bb = bias[col];
      int p = col >> 10, h = (col >> 6) & 15, d = col & 63;
#pragma unroll
      for (int i = 0; i < 2; i++) {
        int rowb = bm * 128 + wm * 64 + i * 32 + 4 * hi;
#pragma unroll
        for (int rq = 0; rq < 4; rq++) {
          int row0 = rowb + 8 * rq;
          int b_ = row0 >> 11, t0 = row0 & 2047;
          if (p == 2) {
            u32x2 pv;
            pv.x = pack2(acc[i][j][rq * 4 + 0] + bb, acc[i][j][rq * 4 + 1] + bb);
            pv.y = pack2(acc[i][j][rq * 4 + 2] + bb, acc[i][j][rq * 4 + 3] + bb);
            *(u32x2*)&VTb[((size_t)(b_ * 16 + h) * 64 + d) * 2048 + t0] = pv;
          } else {
            u16* dst = (p == 0 ? Qb : Kb);
#pragma unroll
            for (int r = 0; r < 4; r++)
              dst[((size_t)(b_ * 16 + h) * 2048 + (t0 + r)) * 64 + d] = f2bf(acc[i][j][rq * 4 + r] + bb);
          }
        }
      }
    }
  } else {           // final projection epilogue: +bias, fp32 out
#pragma unroll
    for (int j = 0; j < 2; j++) {
      int col = bn * 128 + wn * 64 + j * 32 + l31;
      float bb = bias[col];
#pragma unroll
      for (int i = 0; i < 2; i++) {
        int rowb = bm * 128 + wm * 64 + i * 32 + 4 * hi;
#pragma unroll
        for (int rq = 0; rq < 4; rq++)
#pragma unroll
          for (int r = 0; r < 4; r++)
            outF[(size_t)(rowb + 8 * rq + r) * 1024 + col] = acc[i][j][rq * 4 + r] + bb;
      }
    }
  }
}

// ---------------------------------------------------------------- flash attention (causal, 32x32)
// 1024 blocks of 4 waves; block = one 128-row q-tile t (t=0..15) of one (b,h); wave w owns
// rows [128t+32w, +32); iters = 2t+2. Longest-first; 32KB K/V LDS serves 128 q-rows.
// Fully-masked tiles skip compute wave-uniformly; diagonal mask on last two iters only. (R9)
DEV void stage_kv256(const u16* __restrict__ Kh, const u16* __restrict__ Vh, int kv0,
                     u16* Ksb, u16* Vsb, int tid) {
#pragma unroll
  for (int j = 0; j < 2; j++) {
    int ci = j * 256 + tid;                 // 512 chunks of 16B = 64 rows x 8 slots
    int row = ci >> 3, slot = ci & 7;
    int ss = slot ^ (row & 7);
    gll16(Kh + (size_t)(kv0 + row) * 64 + ss * 8, Ksb + ci * 8);
    gll16(Vh + (size_t)row * 2048 + kv0 + ss * 8, Vsb + ci * 8);
  }
}

__global__ __launch_bounds__(256, 2) void attn_kernel(
    const u16* __restrict__ Qb, const u16* __restrict__ Kb, const u16* __restrict__ VTb,
    u16* __restrict__ cat) {
  __shared__ u16 Ks[2][64 * 64];
  __shared__ u16 Vs[2][64 * 64];
  int bid = blockIdx.x;                 // 1024 = 16 t x 64 bh, longest-first
  int t = 15 - (bid >> 6);              // q-tile index: rows [128t, 128t+128)
  int bh = bid & 63;
  int b = bh >> 4, h = bh & 15;
  int tid = threadIdx.x, wave = tid >> 6, lane = tid & 63;
  int l31 = lane & 31, hi = lane >> 5;
  int q0w = t * 128 + wave * 32;        // wave's 32-row q-slice
  int qrow = q0w + l31;

  const u16* Qh = Qb + (size_t)bh * 2048 * 64;
  const u16* Kh = Kb + (size_t)bh * 2048 * 64;
  const u16* Vh = VTb + (size_t)bh * 64 * 2048;

  bf16x8 qf[4];                         // B-operand: col=q (lane&31), k = ks*16 + hi*8 + i
#pragma unroll
  for (int ks = 0; ks < 4; ks++)
    qf[ks] = *(const bf16x8*)&Qh[(size_t)qrow * 64 + ks * 16 + hi * 8];

  u32 loff[4];                          // swizzled LDS byte offsets (row l31; +4096B for +32)
#pragma unroll
  for (int ks = 0; ks < 4; ks++)
    loff[ks] = (u32)(l31 * 128 + (((ks * 2 + hi) ^ (l31 & 7)) * 16));

  f32x16 o0 = zero16(), o1 = zero16();
  float m_run = -1e30f, l_run = 0.f;
  int iters = 2 * t + 2;

  stage_kv256(Kh, Vh, 0, Ks[0], Vs[0], tid);
  __syncthreads();
  int cur = 0;

  for (int kvt = 0; kvt < iters; ++kvt) {
    int kv0 = kvt * 64;
    if (kvt + 1 < iters) stage_kv256(Kh, Vh, kv0 + 64, Ks[cur ^ 1], Vs[cur ^ 1], tid);

    if (kv0 <= q0w + 31) {              // wave-uniform: skip fully-masked tiles
      f32x16 s0 = zero16(), s1 = zero16();
      const char* kb = (const char*)&Ks[cur][0];
      __builtin_amdgcn_s_setprio(1);
#pragma unroll
      for (int ks = 0; ks < 4; ks++) {
        bf16x8 k0 = *(const bf16x8*)(kb + loff[ks]);
        bf16x8 k1 = *(const bf16x8*)(kb + loff[ks] + 4096);
        s0 = __builtin_amdgcn_mfma_f32_32x32x16_bf16(k0, qf[ks], s0, 0, 0, 0);
        s1 = __builtin_amdgcn_mfma_f32_32x32x16_bf16(k1, qf[ks], s1, 0, 0, 0);
      }
      __builtin_amdgcn_s_setprio(0);

      if (kv0 + 63 > q0w) {             // diagonal tile(s) only
        int relh = qrow - kv0 - 4 * hi;
#pragma unroll
        for (int r = 0; r < 16; r++) {
          int off = (r & 3) + 8 * (r >> 2);
          s0[r] = (off > relh) ? -1e30f : s0[r];
          s1[r] = (off + 32 > relh) ? -1e30f : s1[r];
        }
      }

      float ta = max3f(s0[0], s0[1], s0[2]);
      float tb = max3f(s0[4], s0[5], s0[6]);
      float tc = max3f(s0[8], s0[9], s0[10]);
      float td = max3f(s0[12], s0[13], s0[14]);
      ta = max3f(ta, s0[3], s1[0]);
      tb = max3f(tb, s0[7], s1[4]);
      tc = max3f(tc, s0[11], s1[8]);
      td = max3f(td, s0[15], s1[12]);
      ta = max3f(ta, s1[1], s1[2]);
      tb = max3f(tb, s1[5], s1[6]);
      tc = max3f(tc, s1[9], s1[10]);
      td = max3f(td, s1[13], s1[14]);
      ta = max3f(ta, s1[3], tb);
      tc = max3f(tc, s1[7], td);
      float tmax = max3f(ta, tc, s1[11]);
      tmax = fmaxf(tmax, s1[15]);
      tmax = fmaxf(tmax, __shfl_xor(tmax, 32));
      float corr = 1.f;
      if (!__all(tmax <= m_run + 8.f)) {
        float m_new = fmaxf(m_run, tmax);
        corr = exp2_hw(m_run - m_new);
        o0 = o0 * corr;
        o1 = o1 * corr;
        m_run = m_new;
      }
      float t0 = 0.f, t1 = 0.f, t2 = 0.f, t3 = 0.f;
#pragma unroll
      for (int j = 0; j < 4; j++) {
        float p00 = exp2_hw(s0[j * 4 + 0] - m_run); s0[j * 4 + 0] = p00; t0 += p00;
        float p01 = exp2_hw(s0[j * 4 + 1] - m_run); s0[j * 4 + 1] = p01; t1 += p01;
        float p02 = exp2_hw(s0[j * 4 + 2] - m_run); s0[j * 4 + 2] = p02; t2 += p02;
        float p03 = exp2_hw(s0[j * 4 + 3] - m_run); s0[j * 4 + 3] = p03; t3 += p03;
        float p10 = exp2_hw(s1[j * 4 + 0] - m_run); s1[j * 4 + 0] = p10; t0 += p10;
        float p11 = exp2_hw(s1[j * 4 + 1] - m_run); s1[j * 4 + 1] = p11; t1 += p11;
        float p12 = exp2_hw(s1[j * 4 + 2] - m_run); s1[j * 4 + 2] = p12; t2 += p12;
        float p13 = exp2_hw(s1[j * 4 + 3] - m_run); s1[j * 4 + 3] = p13; t3 += p13;
      }
      float ts = (t0 + t1) + (t2 + t3);
      ts += __shfl_xor(ts, 32);
      l_run = l_run * corr + ts;

      const char* vb = (const char*)&Vs[cur][0];
      __builtin_amdgcn_s_setprio(1);
#pragma unroll
      for (int ks = 0; ks < 4; ks++) {
        const f32x16& sb = (ks < 2) ? s0 : s1;
        int g2 = (ks & 1) * 8;
        u32 a  = cvtpk_bf16(sb[g2 + 0], sb[g2 + 1]);
        u32 c  = cvtpk_bf16(sb[g2 + 2], sb[g2 + 3]);
        u32 bb = cvtpk_bf16(sb[g2 + 4], sb[g2 + 5]);
        u32 d  = cvtpk_bf16(sb[g2 + 6], sb[g2 + 7]);
        pl32swap(a, bb);
        pl32swap(c, d);
        u32x4 wv; wv.x = a; wv.y = c; wv.z = bb; wv.w = d;
        bf16x8 pf = __builtin_bit_cast(bf16x8, wv);
        bf16x8 v0 = *(const bf16x8*)(vb + loff[ks]);
        bf16x8 v1 = *(const bf16x8*)(vb + loff[ks] + 4096);
        o0 = __builtin_amdgcn_mfma_f32_32x32x16_bf16(v0, pf, o0, 0, 0, 0);
        o1 = __builtin_amdgcn_mfma_f32_32x32x16_bf16(v1, pf, o1, 0, 0, 0);
      }
      __builtin_amdgcn_s_setprio(0);
    }

    __syncthreads();
    cur ^= 1;
  }

  float li = 1.0f / l_run;
#pragma unroll
  for (int m = 0; m < 8; m++) {
    int dbase = 2 * (m & 1) + 8 * (m >> 1) + 4 * hi;
    u32 w0 = cvtpk_bf16(o0[2 * m] * li, o0[2 * m + 1] * li);
    u32 w1 = cvtpk_bf16(o1[2 * m] * li, o1[2 * m + 1] * li);
    *(u32*)&cat[(size_t)(b * 2048 + qrow) * 1024 + h * 64 + dbase] = w0;
    *(u32*)&cat[(size_t)(b * 2048 + qrow) * 1024 + h * 64 + 32 + dbase] = w1;
  }
}

// ---------------------------------------------------------------- launch
extern "C" void kernel_launch(void* const* d_in, const int* in_sizes, int n_in,
                              void* d_out, int out_size, void* d_ws, size_t ws_size,
                              hipStream_t stream) {
  const float* x  = (const float*)d_in[0];
  const float* Wq = (const float*)d_in[1];
  const float* bq = (const float*)d_in[2];
  const float* Wk = (const float*)d_in[3];
  const float* bk = (const float*)d_in[4];
  const float* Wv = (const float*)d_in[5];
  const float* bv = (const float*)d_in[6];
  const float* Wp = (const float*)d_in[7];
  const float* bp = (const float*)d_in[8];

  char* w = (char*)d_ws;
  u16* xbf    = (u16*)w;                 w += (size_t)8192 * 1024 * 2;
  u16* wqkvT  = (u16*)w;                 w += (size_t)3072 * 1024 * 2;
  u16* wpT    = (u16*)w;                 w += (size_t)1024 * 1024 * 2;
  float* bqkv = (float*)w;               w += (size_t)3072 * 4;
  u16* Qb     = (u16*)w;                 w += (size_t)64 * 2048 * 64 * 2;
  u16* Kb     = (u16*)w;                 w += (size_t)64 * 2048 * 64 * 2;
  u16* VTb    = (u16*)w;                 w += (size_t)64 * 64 * 2048 * 2;
  u16* cat    = (u16*)w;                 w += (size_t)8192 * 1024 * 2;

  prep_all_kernel<<<5120, 256, 0, stream>>>(x, bq, bk, bv, Wq, Wk, Wv, Wp, xbf, bqkv, wqkvT, wpT);
  gemm128_kernel<<<1536, 256, 0, stream>>>(xbf, wqkvT, bqkv, 24, 0, Qb, Kb, VTb, nullptr);
  attn_kernel<<<1024, 256, 0, stream>>>(Qb, Kb, VTb, cat);
  gemm128_kernel<<<512, 256, 0, stream>>>(cat, wpT, bp, 8, 1, nullptr, nullptr, nullptr, (float*)d_out);
}

// Round 15
// 150.658 us; speedup vs baseline: 1.1245x; 1.1016x over previous
//
#include <hip/hip_runtime.h>

// MHA fused forward for B=4,T=2048,E=1024,H=16,D=64 on gfx950.
// Best-measured composition: prep (merged, R11) -> GEMM1 (QKV, R9: 128x128 BK=64 dbuf,
// issue-stage-first, 16x16x32 MFMA, 2 blocks/CU, 0-conflict XOR swizzle) -> flash attn
// (R9: 32x32 MFMA, 4-wave 128-row q-tiles, dbuf K/V, T12/T13) -> GEMM2 (same GEMM).

typedef __attribute__((ext_vector_type(8))) __bf16 bf16x8;
typedef __attribute__((ext_vector_type(4))) float f32x4;
typedef __attribute__((ext_vector_type(16))) float f32x16;
typedef __attribute__((ext_vector_type(4))) unsigned int u32x4;
typedef __attribute__((ext_vector_type(2))) unsigned int u32x2;
typedef unsigned short u16;
typedef unsigned int u32;

#define DEV __device__ __forceinline__

#define QK_SCALE 0.18033688011112042f   // 0.125 * log2(e) : folded into Wq/bq

DEV u16 f2bf(float f) {          // round-to-nearest-even f32 -> bf16 (inputs never NaN)
  u32 u = __builtin_bit_cast(u32, f);
  u += 0x7fffu + ((u >> 16) & 1u);
  return (u16)(u >> 16);
}
DEV u32 pack2(float a, float b) { return (u32)f2bf(a) | ((u32)f2bf(b) << 16); }

DEV float exp2_hw(float x) { float r; asm("v_exp_f32 %0, %1" : "=v"(r) : "v"(x)); return r; }
DEV u32 cvtpk_bf16(float lo, float hi) {
  u32 r; asm("v_cvt_pk_bf16_f32 %0, %1, %2" : "=v"(r) : "v"(lo), "v"(hi)); return r;
}
DEV void pl32swap(u32& a, u32& b) { asm("v_permlane32_swap_b32 %0, %1" : "+v"(a), "+v"(b)); }
DEV float max3f(float a, float b, float c) {
  float r; asm("v_max3_f32 %0, %1, %2, %3" : "=v"(r) : "v"(a), "v"(b), "v"(c)); return r;
}

DEV f32x16 zero16() { f32x16 z;
#pragma unroll
  for (int i = 0; i < 16; i++) z[i] = 0.f;
  return z; }

DEV void gll16(const u16* g, u16* l) {
  __builtin_amdgcn_global_load_lds((const __attribute__((address_space(1))) void*)g,
                                   (__attribute__((address_space(3))) void*)l, 16, 0, 0);
}

// ---------------------------------------------------------------- prep (merged): x->bf16 + biases,
// then weight transposes. Blocks 0..4095: x; 4096..5119: weights.
__global__ __launch_bounds__(256) void prep_all_kernel(
    const float* __restrict__ x, const float* __restrict__ bq, const float* __restrict__ bk,
    const float* __restrict__ bv, const float* __restrict__ Wq, const float* __restrict__ Wk,
    const float* __restrict__ Wv, const float* __restrict__ Wp,
    u16* __restrict__ xbf, float* __restrict__ bqkv, u16* __restrict__ wqkvT, u16* __restrict__ wpT) {
  __shared__ float t[64][65];
  int bidAll = blockIdx.x, tid = threadIdx.x;
  if (bidAll < 4096) {
    int gid = bidAll * 256 + tid;
    if (gid < 3072) {
      float v = (gid < 1024) ? bq[gid] * QK_SCALE : (gid < 2048 ? bk[gid - 1024] : bv[gid - 2048]);
      bqkv[gid] = v;
    }
    const float4* xv = (const float4*)x;
    float4 f0 = xv[(size_t)gid * 2];
    float4 f1 = xv[(size_t)gid * 2 + 1];
    u32x4 st;
    st.x = pack2(f0.x, f0.y); st.y = pack2(f0.z, f0.w);
    st.z = pack2(f1.x, f1.y); st.w = pack2(f1.z, f1.w);
    *(u32x4*)&xbf[(size_t)gid * 8] = st;
    return;
  }
  int bid = bidAll - 4096;
  int r0 = tid >> 6, c = tid & 63;
  if (bid < 768) {
    int p = bid >> 8, rem = bid & 255, h = rem >> 4, et = rem & 15;
    float sc = (p == 0) ? QK_SCALE : 1.0f;
    const float* src = (p == 0 ? Wq : (p == 1 ? Wk : Wv)) + ((size_t)h * 1024 + et * 64) * 64;
#pragma unroll
    for (int i = 0; i < 16; i++) { int e = r0 + i * 4; t[e][c] = src[(size_t)e * 64 + c]; }
    __syncthreads();
    u16* dst = wqkvT + ((size_t)p * 1024 + h * 64) * 1024 + et * 64;
#pragma unroll
    for (int i = 0; i < 16; i++) { int d = r0 + i * 4; dst[(size_t)d * 1024 + c] = f2bf(t[c][d] * sc); }
  } else {
    int b2 = bid - 768, rt = b2 >> 4, ct = b2 & 15;
#pragma unroll
    for (int i = 0; i < 16; i++) { int e = r0 + i * 4; t[e][c] = Wp[(size_t)(rt * 64 + e) * 1024 + ct * 64 + c]; }
    __syncthreads();
#pragma unroll
    for (int i = 0; i < 16; i++) { int f = r0 + i * 4; wpT[(size_t)(ct * 64 + f) * 1024 + rt * 64 + c] = f2bf(t[c][f]); }
  }
}

// ---------------------------------------------------------------- GEMM 128x128, BK=64, dbuf (R9)
// 2 blocks/CU. Loop: issue stage(t+1) into buf^1 FIRST (loads fly under MFMA), ds_read frags,
// 32 MFMA (16x16x32), __syncthreads. XOR swizzle slot^=(row&7) on global source + ds_read
// address (rule #21); 0 bank conflicts measured.
DEV void stage_tile(const u16* __restrict__ X, int row0, int k0, u16* lds, int tid) {
#pragma unroll
  for (int j = 0; j < 4; j++) {
    int ci = j * 256 + tid;
    int row = ci >> 3, slot = ci & 7;
    int srcslot = slot ^ (row & 7);
    gll16(X + (size_t)(row0 + row) * 1024 + k0 + srcslot * 8, lds + ci * 8);
  }
}

__global__ __launch_bounds__(256, 2) void gemm128_kernel(
    const u16* __restrict__ A, const u16* __restrict__ Bt, const float* __restrict__ bias,
    int tilesN, int mode, u16* __restrict__ Qb, u16* __restrict__ Kb, u16* __restrict__ VTb,
    float* __restrict__ outF) {
  __shared__ u16 As[2][128 * 64];
  __shared__ u16 Bs[2][128 * 64];
  int nwg = gridDim.x;
  int bid = blockIdx.x;
  int swz = (bid % 8) * (nwg / 8) + bid / 8;
  int bm = swz / tilesN, bn = swz % tilesN;
  int tid = threadIdx.x;
  int lane = tid & 63, wave = tid >> 6;
  int wm = wave >> 1, wn = wave & 1;
  int lr = lane & 15, lg = lane >> 4;

  f32x4 acc[4][4];
#pragma unroll
  for (int i = 0; i < 4; i++)
#pragma unroll
    for (int j = 0; j < 4; j++) acc[i][j] = f32x4{0.f, 0.f, 0.f, 0.f};

  stage_tile(A, bm * 128, 0, As[0], tid);
  stage_tile(Bt, bn * 128, 0, Bs[0], tid);
  __syncthreads();
  int cur = 0;

  for (int t = 0; t < 16; ++t) {
    if (t + 1 < 16) {             // issue next-tile loads BEFORE compute: fly under MFMA
      stage_tile(A, bm * 128, (t + 1) * 64, As[cur ^ 1], tid);
      stage_tile(Bt, bn * 128, (t + 1) * 64, Bs[cur ^ 1], tid);
    }
#pragma unroll
    for (int kf = 0; kf < 2; kf++) {
      bf16x8 af[4], bfr[4];
#pragma unroll
      for (int i = 0; i < 4; i++) {
        int ra = wm * 64 + i * 16 + lr;
        af[i] = *(const bf16x8*)&As[cur][ra * 64 + (((lg + kf * 4) ^ (ra & 7)) * 8)];
        int rb = wn * 64 + i * 16 + lr;
        bfr[i] = *(const bf16x8*)&Bs[cur][rb * 64 + (((lg + kf * 4) ^ (rb & 7)) * 8)];
      }
      __builtin_amdgcn_s_setprio(1);
#pragma unroll
      for (int i = 0; i < 4; i++)
#pragma unroll
        for (int j = 0; j < 4; j++)
          acc[i][j] = __builtin_amdgcn_mfma_f32_16x16x32_bf16(af[i], bfr[j], acc[i][j], 0, 0, 0);
      __builtin_amdgcn_s_setprio(0);
    }
    __syncthreads();
    cur ^= 1;
  }

  int crow = bm * 128 + wm * 64;
  int ccol = bn * 128 + wn * 64;
  if (mode == 0) {   // QKV epilogue: +bias, ->bf16, scatter Q/K [bh][t][d], V -> VT [bh][d][t]
#pragma unroll
    for (int j = 0; j < 4; j++) {
      int col = ccol + j * 16 + lr;
      float bb = bias[col];
      int p = col >> 10, h = (col >> 6) & 15, d = col & 63;
#pragma unroll
      for (int i = 0; i < 4; i++) {
        int row0 = crow + i * 16 + lg * 4;
        int b_ = row0 >> 11, t0 = row0 & 2047;
        if (p == 2) {
          u32x2 pv;
          pv.x = pack2(acc[i][j][0] + bb, acc[i][j][1] + bb);
          pv.y = pack2(acc[i][j][2] + bb, acc[i][j][3] + bb);
          *(u32x2*)&VTb[((size_t)(b_ * 16 + h) * 64 + d) * 2048 + t0] = pv;
        } else {
          u16* dst = (p == 0 ? Qb : Kb);
#pragma unroll
          for (int r = 0; r < 4; r++)
            dst[((size_t)(b_ * 16 + h) * 2048 + (t0 + r)) * 64 + d] = f2bf(acc[i][j][r] + bb);
        }
      }
    }
  } else {           // final projection epilogue: +bias, fp32 out
#pragma unroll
    for (int j = 0; j < 4; j++) {
      int col = ccol + j * 16 + lr;
      float bb = bias[col];
#pragma unroll
      for (int i = 0; i < 4; i++) {
        int row0 = crow + i * 16 + lg * 4;
#pragma unroll
        for (int r = 0; r < 4; r++)
          outF[(size_t)(row0 + r) * 1024 + col] = acc[i][j][r] + bb;
      }
    }
  }
}

// ---------------------------------------------------------------- flash attention (causal, 32x32) (R9)
// 1024 blocks of 4 waves; block = one 128-row q-tile t (t=0..15) of one (b,h); wave w owns
// rows [128t+32w, +32); iters = 2t+2. Longest-first; 32KB K/V LDS serves 128 q-rows.
// Fully-masked tiles skip compute wave-uniformly; diagonal mask on last two iters only.
DEV void stage_kv256(const u16* __restrict__ Kh, const u16* __restrict__ Vh, int kv0,
                     u16* Ksb, u16* Vsb, int tid) {
#pragma unroll
  for (int j = 0; j < 2; j++) {
    int ci = j * 256 + tid;                 // 512 chunks of 16B = 64 rows x 8 slots
    int row = ci >> 3, slot = ci & 7;
    int ss = slot ^ (row & 7);
    gll16(Kh + (size_t)(kv0 + row) * 64 + ss * 8, Ksb + ci * 8);
    gll16(Vh + (size_t)row * 2048 + kv0 + ss * 8, Vsb + ci * 8);
  }
}

__global__ __launch_bounds__(256, 2) void attn_kernel(
    const u16* __restrict__ Qb, const u16* __restrict__ Kb, const u16* __restrict__ VTb,
    u16* __restrict__ cat) {
  __shared__ u16 Ks[2][64 * 64];
  __shared__ u16 Vs[2][64 * 64];
  int bid = blockIdx.x;                 // 1024 = 16 t x 64 bh, longest-first
  int t = 15 - (bid >> 6);              // q-tile index: rows [128t, 128t+128)
  int bh = bid & 63;
  int b = bh >> 4, h = bh & 15;
  int tid = threadIdx.x, wave = tid >> 6, lane = tid & 63;
  int l31 = lane & 31, hi = lane >> 5;
  int q0w = t * 128 + wave * 32;        // wave's 32-row q-slice
  int qrow = q0w + l31;

  const u16* Qh = Qb + (size_t)bh * 2048 * 64;
  const u16* Kh = Kb + (size_t)bh * 2048 * 64;
  const u16* Vh = VTb + (size_t)bh * 64 * 2048;

  bf16x8 qf[4];                         // B-operand: col=q (lane&31), k = ks*16 + hi*8 + i
#pragma unroll
  for (int ks = 0; ks < 4; ks++)
    qf[ks] = *(const bf16x8*)&Qh[(size_t)qrow * 64 + ks * 16 + hi * 8];

  u32 loff[4];                          // swizzled LDS byte offsets (row l31; +4096B for +32)
#pragma unroll
  for (int ks = 0; ks < 4; ks++)
    loff[ks] = (u32)(l31 * 128 + (((ks * 2 + hi) ^ (l31 & 7)) * 16));

  f32x16 o0 = zero16(), o1 = zero16();
  float m_run = -1e30f, l_run = 0.f;
  int iters = 2 * t + 2;

  stage_kv256(Kh, Vh, 0, Ks[0], Vs[0], tid);
  __syncthreads();
  int cur = 0;

  for (int kvt = 0; kvt < iters; ++kvt) {
    int kv0 = kvt * 64;
    if (kvt + 1 < iters) stage_kv256(Kh, Vh, kv0 + 64, Ks[cur ^ 1], Vs[cur ^ 1], tid);

    if (kv0 <= q0w + 31) {              // wave-uniform: skip fully-masked tiles
      f32x16 s0 = zero16(), s1 = zero16();
      const char* kb = (const char*)&Ks[cur][0];
      __builtin_amdgcn_s_setprio(1);
#pragma unroll
      for (int ks = 0; ks < 4; ks++) {
        bf16x8 k0 = *(const bf16x8*)(kb + loff[ks]);
        bf16x8 k1 = *(const bf16x8*)(kb + loff[ks] + 4096);
        s0 = __builtin_amdgcn_mfma_f32_32x32x16_bf16(k0, qf[ks], s0, 0, 0, 0);
        s1 = __builtin_amdgcn_mfma_f32_32x32x16_bf16(k1, qf[ks], s1, 0, 0, 0);
      }
      __builtin_amdgcn_s_setprio(0);

      if (kv0 + 63 > q0w) {             // diagonal tile(s) only
        int relh = qrow - kv0 - 4 * hi;
#pragma unroll
        for (int r = 0; r < 16; r++) {
          int off = (r & 3) + 8 * (r >> 2);
          s0[r] = (off > relh) ? -1e30f : s0[r];
          s1[r] = (off + 32 > relh) ? -1e30f : s1[r];
        }
      }

      float ta = max3f(s0[0], s0[1], s0[2]);
      float tb = max3f(s0[4], s0[5], s0[6]);
      float tc = max3f(s0[8], s0[9], s0[10]);
      float td = max3f(s0[12], s0[13], s0[14]);
      ta = max3f(ta, s0[3], s1[0]);
      tb = max3f(tb, s0[7], s1[4]);
      tc = max3f(tc, s0[11], s1[8]);
      td = max3f(td, s0[15], s1[12]);
      ta = max3f(ta, s1[1], s1[2]);
      tb = max3f(tb, s1[5], s1[6]);
      tc = max3f(tc, s1[9], s1[10]);
      td = max3f(td, s1[13], s1[14]);
      ta = max3f(ta, s1[3], tb);
      tc = max3f(tc, s1[7], td);
      float tmax = max3f(ta, tc, s1[11]);
      tmax = fmaxf(tmax, s1[15]);
      tmax = fmaxf(tmax, __shfl_xor(tmax, 32));
      float corr = 1.f;
      if (!__all(tmax <= m_run + 8.f)) {
        float m_new = fmaxf(m_run, tmax);
        corr = exp2_hw(m_run - m_new);
        o0 = o0 * corr;
        o1 = o1 * corr;
        m_run = m_new;
      }
      float t0 = 0.f, t1 = 0.f, t2 = 0.f, t3 = 0.f;
#pragma unroll
      for (int j = 0; j < 4; j++) {
        float p00 = exp2_hw(s0[j * 4 + 0] - m_run); s0[j * 4 + 0] = p00; t0 += p00;
        float p01 = exp2_hw(s0[j * 4 + 1] - m_run); s0[j * 4 + 1] = p01; t1 += p01;
        float p02 = exp2_hw(s0[j * 4 + 2] - m_run); s0[j * 4 + 2] = p02; t2 += p02;
        float p03 = exp2_hw(s0[j * 4 + 3] - m_run); s0[j * 4 + 3] = p03; t3 += p03;
        float p10 = exp2_hw(s1[j * 4 + 0] - m_run); s1[j * 4 + 0] = p10; t0 += p10;
        float p11 = exp2_hw(s1[j * 4 + 1] - m_run); s1[j * 4 + 1] = p11; t1 += p11;
        float p12 = exp2_hw(s1[j * 4 + 2] - m_run); s1[j * 4 + 2] = p12; t2 += p12;
        float p13 = exp2_hw(s1[j * 4 + 3] - m_run); s1[j * 4 + 3] = p13; t3 += p13;
      }
      float ts = (t0 + t1) + (t2 + t3);
      ts += __shfl_xor(ts, 32);
      l_run = l_run * corr + ts;

      const char* vb = (const char*)&Vs[cur][0];
      __builtin_amdgcn_s_setprio(1);
#pragma unroll
      for (int ks = 0; ks < 4; ks++) {
        const f32x16& sb = (ks < 2) ? s0 : s1;
        int g2 = (ks & 1) * 8;
        u32 a  = cvtpk_bf16(sb[g2 + 0], sb[g2 + 1]);
        u32 c  = cvtpk_bf16(sb[g2 + 2], sb[g2 + 3]);
        u32 bb = cvtpk_bf16(sb[g2 + 4], sb[g2 + 5]);
        u32 d  = cvtpk_bf16(sb[g2 + 6], sb[g2 + 7]);
        pl32swap(a, bb);
        pl32swap(c, d);
        u32x4 wv; wv.x = a; wv.y = c; wv.z = bb; wv.w = d;
        bf16x8 pf = __builtin_bit_cast(bf16x8, wv);
        bf16x8 v0 = *(const bf16x8*)(vb + loff[ks]);
        bf16x8 v1 = *(const bf16x8*)(vb + loff[ks] + 4096);
        o0 = __builtin_amdgcn_mfma_f32_32x32x16_bf16(v0, pf, o0, 0, 0, 0);
        o1 = __builtin_amdgcn_mfma_f32_32x32x16_bf16(v1, pf, o1, 0, 0, 0);
      }
      __builtin_amdgcn_s_setprio(0);
    }

    __syncthreads();
    cur ^= 1;
  }

  float li = 1.0f / l_run;
#pragma unroll
  for (int m = 0; m < 8; m++) {
    int dbase = 2 * (m & 1) + 8 * (m >> 1) + 4 * hi;
    u32 w0 = cvtpk_bf16(o0[2 * m] * li, o0[2 * m + 1] * li);
    u32 w1 = cvtpk_bf16(o1[2 * m] * li, o1[2 * m + 1] * li);
    *(u32*)&cat[(size_t)(b * 2048 + qrow) * 1024 + h * 64 + dbase] = w0;
    *(u32*)&cat[(size_t)(b * 2048 + qrow) * 1024 + h * 64 + 32 + dbase] = w1;
  }
}

// ---------------------------------------------------------------- launch
extern "C" void kernel_launch(void* const* d_in, const int* in_sizes, int n_in,
                              void* d_out, int out_size, void* d_ws, size_t ws_size,
                              hipStream_t stream) {
  const float* x  = (const float*)d_in[0];
  const float* Wq = (const float*)d_in[1];
  const float* bq = (const float*)d_in[2];
  const float* Wk = (const float*)d_in[3];
  const float* bk = (const float*)d_in[4];
  const float* Wv = (const float*)d_in[5];
  const float* bv = (const float*)d_in[6];
  const float* Wp = (const float*)d_in[7];
  const float* bp = (const float*)d_in[8];

  char* w = (char*)d_ws;
  u16* xbf    = (u16*)w;                 w += (size_t)8192 * 1024 * 2;
  u16* wqkvT  = (u16*)w;                 w += (size_t)3072 * 1024 * 2;
  u16* wpT    = (u16*)w;                 w += (size_t)1024 * 1024 * 2;
  float* bqkv = (float*)w;               w += (size_t)3072 * 4;
  u16* Qb     = (u16*)w;                 w += (size_t)64 * 2048 * 64 * 2;
  u16* Kb     = (u16*)w;                 w += (size_t)64 * 2048 * 64 * 2;
  u16* VTb    = (u16*)w;                 w += (size_t)64 * 64 * 2048 * 2;
  u16* cat    = (u16*)w;                 w += (size_t)8192 * 1024 * 2;

  prep_all_kernel<<<5120, 256, 0, stream>>>(x, bq, bk, bv, Wq, Wk, Wv, Wp, xbf, bqkv, wqkvT, wpT);
  gemm128_kernel<<<1536, 256, 0, stream>>>(xbf, wqkvT, bqkv, 24, 0, Qb, Kb, VTb, nullptr);
  attn_kernel<<<1024, 256, 0, stream>>>(Qb, Kb, VTb, cat);
  gemm128_kernel<<<512, 256, 0, stream>>>(cat, wpT, bp, 8, 1, nullptr, nullptr, nullptr, (float*)d_out);
}